// Round 7
// baseline (52.687 us; speedup 1.0000x reference)
//
#include <hip/hip_runtime.h>

#define HW_N     (512 * 512)   // 262144 mask elements
#define ROWS     512           // B*C
#define NINST    63            // ids 1..63
#define NCHUNK   256
#define CHUNK    1024          // NCHUNK*CHUNK == HW_N

// ws int layout:
//  [320..383]=valid   [384..447]=losses (float, via wsf)
//  [448]=grid-barrier counter  [449]=done-counter   (both memset to 0 per call)
//  [1024..1024+16384)=hist[inst][chunk]  (transposed: contiguous per inst)
#define WS_BAR   448
#define WS_CTR   449
#define WS_HIST  1024

// -------- Threefry-2x32, 20 rounds (exact JAX partitionable semantics) ------
__device__ __forceinline__ unsigned rotl32(unsigned v, int r) {
    return (v << r) | (v >> (32 - r));
}

__device__ void threefry2x32(unsigned k0, unsigned k1,
                             unsigned x0, unsigned x1,
                             unsigned* o0, unsigned* o1) {
    const unsigned ks0 = k0, ks1 = k1;
    const unsigned ks2 = k0 ^ k1 ^ 0x1BD11BDAu;
    x0 += ks0; x1 += ks1;
    x0 += x1; x1 = rotl32(x1, 13); x1 ^= x0;
    x0 += x1; x1 = rotl32(x1, 15); x1 ^= x0;
    x0 += x1; x1 = rotl32(x1, 26); x1 ^= x0;
    x0 += x1; x1 = rotl32(x1,  6); x1 ^= x0;
    x0 += ks1; x1 += ks2 + 1u;
    x0 += x1; x1 = rotl32(x1, 17); x1 ^= x0;
    x0 += x1; x1 = rotl32(x1, 29); x1 ^= x0;
    x0 += x1; x1 = rotl32(x1, 16); x1 ^= x0;
    x0 += x1; x1 = rotl32(x1, 24); x1 ^= x0;
    x0 += ks2; x1 += ks0 + 2u;
    x0 += x1; x1 = rotl32(x1, 13); x1 ^= x0;
    x0 += x1; x1 = rotl32(x1, 15); x1 ^= x0;
    x0 += x1; x1 = rotl32(x1, 26); x1 ^= x0;
    x0 += x1; x1 = rotl32(x1,  6); x1 ^= x0;
    x0 += ks0; x1 += ks1 + 3u;
    x0 += x1; x1 = rotl32(x1, 17); x1 ^= x0;
    x0 += x1; x1 = rotl32(x1, 29); x1 ^= x0;
    x0 += x1; x1 = rotl32(x1, 16); x1 ^= x0;
    x0 += x1; x1 = rotl32(x1, 24); x1 ^= x0;
    x0 += ks1; x1 += ks2 + 4u;
    x0 += x1; x1 = rotl32(x1, 13); x1 ^= x0;
    x0 += x1; x1 = rotl32(x1, 15); x1 ^= x0;
    x0 += x1; x1 = rotl32(x1, 26); x1 ^= x0;
    x0 += x1; x1 = rotl32(x1,  6); x1 ^= x0;
    x0 += ks2; x1 += ks0 + 5u;
    *o0 = x0; *o1 = x1;
}

// inclusive block scan over 256 threads (4 waves), shfl-based
__device__ int block_scan_incl(int x, int tid, int* wsum /*LDS[4]*/) {
    const int lane = tid & 63, wid = tid >> 6;
    for (int off = 1; off < 64; off <<= 1) {
        int y = __shfl_up(x, off, 64);
        if (lane >= off) x += y;
    }
    if (lane == 63) wsum[wid] = x;
    __syncthreads();
    int add = 0;
    for (int w = 0; w < wid; w++) add += wsum[w];
    x += add;
    __syncthreads();            // wsum reusable by the next call
    return x;
}

__global__ __launch_bounds__(256, 1)
void icl_fused_kernel(const int* __restrict__ mask,
                      const float* __restrict__ feats,
                      int* __restrict__ ws,
                      float* __restrict__ wsf,
                      float* __restrict__ out) {
    const int bid = blockIdx.x;
    const int tid = threadIdx.x;

    __shared__ int h[64];
    __shared__ int wsum[4];
    __shared__ int s_cnt;
    __shared__ unsigned s_r;
    __shared__ int s_ch[3], s_k[3], s_idx[3];
    __shared__ float sred[8];
    __shared__ int s_last;

    // ============ phase 1: per-chunk histogram, transposed store ============
    if (tid < 64) h[tid] = 0;
    __syncthreads();
    {
        const int4 v = ((const int4*)(mask + bid * CHUNK))[tid];
        if ((unsigned)v.x < 64u) atomicAdd(&h[v.x], 1);
        if ((unsigned)v.y < 64u) atomicAdd(&h[v.y], 1);
        if ((unsigned)v.z < 64u) atomicAdd(&h[v.z], 1);
        if ((unsigned)v.w < 64u) atomicAdd(&h[v.w], 1);
    }
    __syncthreads();
    if (tid < 64) ws[WS_HIST + tid * NCHUNK + bid] = h[tid];

    // ============ homemade grid barrier (256 co-resident blocks) ============
    // counters are zeroed by a memset node before this kernel each call.
    if (tid == 0) {
        __threadfence();                                   // release hist stores
        atomicAdd((unsigned*)&ws[WS_BAR], 1u);
        while (__hip_atomic_load((unsigned*)&ws[WS_BAR],
                                 __ATOMIC_ACQUIRE, __HIP_MEMORY_SCOPE_AGENT)
               < (unsigned)NCHUNK) {
            __builtin_amdgcn_s_sleep(1);
        }
    }
    __syncthreads();
    __threadfence();                                       // acquire hist stores

    if (bid >= NINST) return;

    // ============ phase 2: per-inst setup + resolve + dist ==================
    const int inst = bid + 1;
    if (tid == 0) {
        s_ch[0] = s_ch[1] = s_ch[2] = -1;
        s_k[0] = 1; s_k[1] = 0; s_k[2] = 0;
        s_idx[0] = s_idx[1] = s_idx[2] = 0;
    }

    // scan per-chunk hist for this inst (contiguous 1KB read)
    const int hh = ws[WS_HIST + inst * NCHUNK + tid];
    const int incl = block_scan_incl(hh, tid, wsum);   // has barriers (defaults visible)
    const int excl = incl - hh;
    if (tid == 255) s_cnt = incl;
    if (excl == 0 && incl >= 1) s_ch[0] = tid;                       // rank-1 match
    if (excl < 2 && incl >= 2) { s_ch[1] = tid; s_k[1] = 2 - excl; } // rank-2 match
    __syncthreads();

    const int cnt = s_cnt;
    const int ncnt = HW_N - cnt;
    if (tid == 0) {
        unsigned span = (unsigned)((ncnt > 1) ? ncnt : 1);
        unsigned f0, f1, k1a, k1b, k2a, k2b, h0, h1, l0, l1;
        threefry2x32(0u, 42u, 0u, (unsigned)inst, &f0, &f1);
        threefry2x32(f0, f1, 0u, 0u, &k1a, &k1b);
        threefry2x32(f0, f1, 0u, 1u, &k2a, &k2b);
        threefry2x32(k1a, k1b, 0u, 0u, &h0, &h1);
        threefry2x32(k2a, k2b, 0u, 0u, &l0, &l1);
        const unsigned hi = h0 ^ h1, lo = l0 ^ l1;
        unsigned mult = 65536u % span;
        mult = (mult * mult) % span;
        s_r = ((hi % span) * mult + (lo % span)) % span;
    }
    __syncthreads();

    // negative: (r+1)-th nonmatch
    const long long target = (long long)s_r + 1;
    const long long negincl = (long long)(tid + 1) * CHUNK - incl;
    const long long negexcl = (long long)tid * CHUNK - excl;
    if (negexcl < target && target <= negincl) {
        s_ch[2] = tid; s_k[2] = (int)(target - negexcl);
    }
    __syncthreads();

    // prefetch all three chunks (independent loads, hide latency)
    int4 vt[3];
    #pragma unroll
    for (int t = 0; t < 3; t++) {
        const int chunk = s_ch[t];
        if (chunk >= 0) vt[t] = ((const int4*)(mask + chunk * CHUNK))[tid];
    }

    // resolve the 3 in-chunk rank-selects
    #pragma unroll
    for (int t = 0; t < 3; t++) {
        const int chunk = s_ch[t];          // block-uniform
        if (chunk >= 0) {
            const int k = s_k[t];
            const int4 v = vt[t];
            int f0 = (v.x == inst), f1 = (v.y == inst), f2 = (v.z == inst), f3 = (v.w == inst);
            if (t == 2) { f0 = !f0; f1 = !f1; f2 = !f2; f3 = !f3; }
            const int mycnt = f0 + f1 + f2 + f3;
            const int minc = block_scan_incl(mycnt, tid, wsum);
            const int mexc = minc - mycnt;
            if (mexc < k && k <= minc) {
                int need = k - mexc, j = 3;
                if (f0 && --need == 0) j = 0;
                else if (f1 && --need == 0) j = 1;
                else if (f2 && --need == 0) j = 2;
                s_idx[t] = chunk * CHUNK + tid * 4 + j;
            }
        }
        __syncthreads();
    }

    // dist: gather 3 columns, hinge
    const int valid = (cnt >= 2 && ncnt > 0) ? 1 : 0;
    const int iF = s_idx[0], iS = s_idx[1], iN = s_idx[2];
    float sap = 0.f, san = 0.f;
    if (valid) {
        for (int row = tid; row < ROWS; row += 256) {
            const size_t off = (size_t)row * HW_N;
            const float a = feats[off + iF];
            const float p = feats[off + iS];
            const float n = feats[off + iN];
            const float dp = a - p + 1e-6f;
            const float dn = a - n + 1e-6f;
            sap += dp * dp;
            san += dn * dn;
        }
    }
    for (int off = 32; off > 0; off >>= 1) {
        sap += __shfl_down(sap, off, 64);
        san += __shfl_down(san, off, 64);
    }
    const int lane = tid & 63, wid = tid >> 6;
    if (lane == 0) { sred[wid] = sap; sred[4 + wid] = san; }
    __syncthreads();
    if (tid == 0) {
        float t1 = sred[0] + sred[1] + sred[2] + sred[3];
        float t2 = sred[4] + sred[5] + sred[6] + sred[7];
        const float l = fmaxf(sqrtf(t1) - sqrtf(t2) + 1.0f, 0.0f);
        wsf[inst] = valid ? l : 0.0f;
        ws[320 + inst] = valid;
        __threadfence();                                     // release
        const unsigned old = atomicAdd((unsigned*)&ws[WS_CTR], 1u);
        s_last = (old == NINST - 1);
    }
    __syncthreads();

    // elected last block: deterministic final mean (fixed-order tree)
    if (s_last && tid < 64) {
        __threadfence();                                     // acquire
        float l = 0.f, v = 0.f;
        if (tid >= 1 && tid <= NINST) {
            l = __hip_atomic_load(&wsf[tid], __ATOMIC_RELAXED, __HIP_MEMORY_SCOPE_AGENT);
            v = (float)__hip_atomic_load(&ws[320 + tid], __ATOMIC_RELAXED, __HIP_MEMORY_SCOPE_AGENT);
        }
        for (int off = 32; off > 0; off >>= 1) {
            l += __shfl_down(l, off, 64);
            v += __shfl_down(v, off, 64);
        }
        if (tid == 0) out[0] = (v > 0.f) ? (l / fmaxf(v, 1.0f)) : 0.0f;
    }
}

extern "C" void kernel_launch(void* const* d_in, const int* in_sizes, int n_in,
                              void* d_out, int out_size, void* d_ws, size_t ws_size,
                              hipStream_t stream) {
    const float* feats = (const float*)d_in[0];   // (2,256,512,512) f32 -> (512, 262144)
    const int*   mask  = (const int*)d_in[1];     // (512,512) int32
    float* out = (float*)d_out;
    int*   wsi = (int*)d_ws;
    float* wsf = ((float*)d_ws) + 384;

    // zero the barrier + done counters (deterministic per replay)
    hipMemsetAsync((void*)(wsi + WS_BAR), 0, 2 * sizeof(int), stream);
    icl_fused_kernel<<<NCHUNK, 256, 0, stream>>>(mask, feats, wsi, wsf, out);
}

// Round 8
// 46.569 us; speedup vs baseline: 1.1314x; 1.1314x over previous
//
#include <hip/hip_runtime.h>

#define HW_N     (512 * 512)   // 262144 mask elements
#define ROWS     512           // B*C
#define NINST    63            // ids 1..63
#define NTHR     1024          // threads per block
#define SEG      256           // elements per thread
#define SEGI4    64            // int4 per thread

// ws int layout: [320..383]=valid  [384..447]=losses (float, via wsf)
//                [448]=done-counter (memset to 0 per call)
#define WS_CTR   448

// -------- Threefry-2x32, 20 rounds (exact JAX partitionable semantics) ------
__device__ __forceinline__ unsigned rotl32(unsigned v, int r) {
    return (v << r) | (v >> (32 - r));
}

__device__ void threefry2x32(unsigned k0, unsigned k1,
                             unsigned x0, unsigned x1,
                             unsigned* o0, unsigned* o1) {
    const unsigned ks0 = k0, ks1 = k1;
    const unsigned ks2 = k0 ^ k1 ^ 0x1BD11BDAu;
    x0 += ks0; x1 += ks1;
    x0 += x1; x1 = rotl32(x1, 13); x1 ^= x0;
    x0 += x1; x1 = rotl32(x1, 15); x1 ^= x0;
    x0 += x1; x1 = rotl32(x1, 26); x1 ^= x0;
    x0 += x1; x1 = rotl32(x1,  6); x1 ^= x0;
    x0 += ks1; x1 += ks2 + 1u;
    x0 += x1; x1 = rotl32(x1, 17); x1 ^= x0;
    x0 += x1; x1 = rotl32(x1, 29); x1 ^= x0;
    x0 += x1; x1 = rotl32(x1, 16); x1 ^= x0;
    x0 += x1; x1 = rotl32(x1, 24); x1 ^= x0;
    x0 += ks2; x1 += ks0 + 2u;
    x0 += x1; x1 = rotl32(x1, 13); x1 ^= x0;
    x0 += x1; x1 = rotl32(x1, 15); x1 ^= x0;
    x0 += x1; x1 = rotl32(x1, 26); x1 ^= x0;
    x0 += x1; x1 = rotl32(x1,  6); x1 ^= x0;
    x0 += ks0; x1 += ks1 + 3u;
    x0 += x1; x1 = rotl32(x1, 17); x1 ^= x0;
    x0 += x1; x1 = rotl32(x1, 29); x1 ^= x0;
    x0 += x1; x1 = rotl32(x1, 16); x1 ^= x0;
    x0 += x1; x1 = rotl32(x1, 24); x1 ^= x0;
    x0 += ks1; x1 += ks2 + 4u;
    x0 += x1; x1 = rotl32(x1, 13); x1 ^= x0;
    x0 += x1; x1 = rotl32(x1, 15); x1 ^= x0;
    x0 += x1; x1 = rotl32(x1, 26); x1 ^= x0;
    x0 += x1; x1 = rotl32(x1,  6); x1 ^= x0;
    x0 += ks2; x1 += ks0 + 5u;
    *o0 = x0; *o1 = x1;
}

__global__ __launch_bounds__(NTHR, 1)
void icl_one_kernel(const int* __restrict__ mask,
                    const float* __restrict__ feats,
                    int* __restrict__ ws,
                    float* __restrict__ wsf,
                    float* __restrict__ out) {
    const int inst = blockIdx.x + 1;
    const int tid  = threadIdx.x;
    const int lane = tid & 63, wid = tid >> 6;   // 16 waves

    __shared__ int s_wsum[16];
    __shared__ int s_cnt;
    __shared__ unsigned s_r;
    __shared__ int s_task_tid[3], s_task_k[3], s_idx[3];
    __shared__ float sred[32];
    __shared__ int s_last;

    if (tid < 3) { s_task_tid[tid] = -1; s_idx[tid] = 0; }

    // ---- pass 1: count matches in my contiguous 256-element segment ----
    const int4* mp = (const int4*)mask + tid * SEGI4;
    int m = 0;
    #pragma unroll 4
    for (int j = 0; j < SEGI4; j++) {
        const int4 v = mp[j];
        m += (v.x == inst) + (v.y == inst) + (v.z == inst) + (v.w == inst);
    }

    // ---- block scan of per-thread match counts (16 waves) ----
    int x = m;
    for (int off = 1; off < 64; off <<= 1) {
        int y = __shfl_up(x, off, 64);
        if (lane >= off) x += y;
    }
    if (lane == 63) s_wsum[wid] = x;
    __syncthreads();
    int add = 0;
    for (int w = 0; w < wid; w++) add += s_wsum[w];
    const int incl = x + add;
    const int excl = incl - m;
    if (tid == NTHR - 1) s_cnt = incl;
    __syncthreads();

    const int cnt  = s_cnt;
    const int ncnt = HW_N - cnt;

    // ---- Threefry randint (one thread) ----
    if (tid == 0) {
        unsigned span = (unsigned)((ncnt > 1) ? ncnt : 1);
        unsigned f0, f1, k1a, k1b, k2a, k2b, h0, h1, l0, l1;
        threefry2x32(0u, 42u, 0u, (unsigned)inst, &f0, &f1);
        threefry2x32(f0, f1, 0u, 0u, &k1a, &k1b);
        threefry2x32(f0, f1, 0u, 1u, &k2a, &k2b);
        threefry2x32(k1a, k1b, 0u, 0u, &h0, &h1);
        threefry2x32(k2a, k2b, 0u, 0u, &l0, &l1);
        const unsigned hi = h0 ^ h1, lo = l0 ^ l1;
        unsigned mult = 65536u % span;
        mult = (mult * mult) % span;
        s_r = ((hi % span) * mult + (lo % span)) % span;
    }
    __syncthreads();

    // ---- task owners: rank-1 match, rank-2 match, rank-(r+1) negative ----
    if (excl == 0 && incl >= 1) { s_task_tid[0] = tid; s_task_k[0] = 1; }
    if (excl <  2 && incl >= 2) { s_task_tid[1] = tid; s_task_k[1] = 2 - excl; }
    const long long target = (long long)s_r + 1;
    const long long nexcl  = (long long)tid * SEG - excl;
    const long long nincl  = nexcl + (SEG - m);
    if (nexcl < target && target <= nincl) {
        s_task_tid[2] = tid; s_task_k[2] = (int)(target - nexcl);
    }
    __syncthreads();

    // ---- resolve: owning thread's wave does a coalesced 1KB read + select --
    #pragma unroll
    for (int t = 0; t < 3; t++) {
        const int ot = s_task_tid[t];
        if (ot >= 0 && (ot >> 6) == wid) {        // wave-uniform condition
            const int k = s_task_k[t];
            const int4 v = ((const int4*)mask)[ot * SEGI4 + lane];
            int f0 = (v.x == inst), f1 = (v.y == inst),
                f2 = (v.z == inst), f3 = (v.w == inst);
            if (t == 2) { f0 = !f0; f1 = !f1; f2 = !f2; f3 = !f3; }
            const int pc = f0 + f1 + f2 + f3;
            int sx = pc;
            for (int off = 1; off < 64; off <<= 1) {
                int y = __shfl_up(sx, off, 64);
                if (lane >= off) sx += y;
            }
            const int pre = sx - pc;
            if (pre < k && k <= sx) {
                int need = k - pre, j = 3;
                if (f0 && --need == 0) j = 0;
                else if (f1 && --need == 0) j = 1;
                else if (f2 && --need == 0) j = 2;
                s_idx[t] = ot * SEG + lane * 4 + j;
            }
        }
    }
    __syncthreads();

    // ---- gather 3 feature columns, hinge ----
    const int valid = (cnt >= 2 && ncnt > 0) ? 1 : 0;
    const int iF = s_idx[0], iS = s_idx[1], iN = s_idx[2];
    float sap = 0.f, san = 0.f;
    if (valid && tid < ROWS) {
        const size_t off = (size_t)tid * HW_N;
        const float a = feats[off + iF];
        const float p = feats[off + iS];
        const float n = feats[off + iN];
        const float dp = a - p + 1e-6f;
        const float dn = a - n + 1e-6f;
        sap = dp * dp;
        san = dn * dn;
    }
    for (int off = 32; off > 0; off >>= 1) {
        sap += __shfl_down(sap, off, 64);
        san += __shfl_down(san, off, 64);
    }
    if (lane == 0) { sred[wid] = sap; sred[16 + wid] = san; }
    __syncthreads();
    if (tid == 0) {
        float t1 = 0.f, t2 = 0.f;
        for (int w = 0; w < 16; w++) { t1 += sred[w]; t2 += sred[16 + w]; }
        const float l = fmaxf(sqrtf(t1) - sqrtf(t2) + 1.0f, 0.0f);
        wsf[inst] = valid ? l : 0.0f;
        ws[320 + inst] = valid;
        __threadfence();                                     // release
        const unsigned old = atomicAdd((unsigned*)&ws[WS_CTR], 1u);
        s_last = (old == NINST - 1);
    }
    __syncthreads();

    // ---- elected last block: deterministic final mean (fixed-order tree) ----
    if (s_last && tid < 64) {
        __threadfence();                                     // acquire
        float l = 0.f, v = 0.f;
        if (tid >= 1 && tid <= NINST) {
            l = __hip_atomic_load(&wsf[tid], __ATOMIC_RELAXED, __HIP_MEMORY_SCOPE_AGENT);
            v = (float)__hip_atomic_load(&ws[320 + tid], __ATOMIC_RELAXED, __HIP_MEMORY_SCOPE_AGENT);
        }
        for (int off = 32; off > 0; off >>= 1) {
            l += __shfl_down(l, off, 64);
            v += __shfl_down(v, off, 64);
        }
        if (tid == 0) out[0] = (v > 0.f) ? (l / fmaxf(v, 1.0f)) : 0.0f;
    }
}

extern "C" void kernel_launch(void* const* d_in, const int* in_sizes, int n_in,
                              void* d_out, int out_size, void* d_ws, size_t ws_size,
                              hipStream_t stream) {
    const float* feats = (const float*)d_in[0];   // (2,256,512,512) f32 -> (512, 262144)
    const int*   mask  = (const int*)d_in[1];     // (512,512) int32
    float* out = (float*)d_out;
    int*   wsi = (int*)d_ws;
    float* wsf = ((float*)d_ws) + 384;

    // zero the done-counter (deterministic per replay)
    hipMemsetAsync((void*)(wsi + WS_CTR), 0, sizeof(int), stream);
    icl_one_kernel<<<NINST, NTHR, 0, stream>>>(mask, feats, wsi, wsf, out);
}

// Round 9
// 18.372 us; speedup vs baseline: 2.8677x; 2.5348x over previous
//
#include <hip/hip_runtime.h>

#define HW_N     (512 * 512)   // 262144 mask elements
#define ROWS     512           // B*C
#define NINST    63            // ids 1..63
#define NCHUNK   256
#define CHUNK    1024          // NCHUNK*CHUNK == HW_N

// ws int layout:
//  [320..383]=valid   [384..447]=losses (float, via wsf)   [448]=done-counter
//  [1024..1024+16384)=hist[inst][chunk]  (transposed: contiguous per inst)
#define WS_CTR   448
#define WS_HIST  1024

// -------- Threefry-2x32, 20 rounds (exact JAX partitionable semantics) ------
__device__ __forceinline__ unsigned rotl32(unsigned v, int r) {
    return (v << r) | (v >> (32 - r));
}

__device__ void threefry2x32(unsigned k0, unsigned k1,
                             unsigned x0, unsigned x1,
                             unsigned* o0, unsigned* o1) {
    const unsigned ks0 = k0, ks1 = k1;
    const unsigned ks2 = k0 ^ k1 ^ 0x1BD11BDAu;
    x0 += ks0; x1 += ks1;
    x0 += x1; x1 = rotl32(x1, 13); x1 ^= x0;
    x0 += x1; x1 = rotl32(x1, 15); x1 ^= x0;
    x0 += x1; x1 = rotl32(x1, 26); x1 ^= x0;
    x0 += x1; x1 = rotl32(x1,  6); x1 ^= x0;
    x0 += ks1; x1 += ks2 + 1u;
    x0 += x1; x1 = rotl32(x1, 17); x1 ^= x0;
    x0 += x1; x1 = rotl32(x1, 29); x1 ^= x0;
    x0 += x1; x1 = rotl32(x1, 16); x1 ^= x0;
    x0 += x1; x1 = rotl32(x1, 24); x1 ^= x0;
    x0 += ks2; x1 += ks0 + 2u;
    x0 += x1; x1 = rotl32(x1, 13); x1 ^= x0;
    x0 += x1; x1 = rotl32(x1, 15); x1 ^= x0;
    x0 += x1; x1 = rotl32(x1, 26); x1 ^= x0;
    x0 += x1; x1 = rotl32(x1,  6); x1 ^= x0;
    x0 += ks0; x1 += ks1 + 3u;
    x0 += x1; x1 = rotl32(x1, 17); x1 ^= x0;
    x0 += x1; x1 = rotl32(x1, 29); x1 ^= x0;
    x0 += x1; x1 = rotl32(x1, 16); x1 ^= x0;
    x0 += x1; x1 = rotl32(x1, 24); x1 ^= x0;
    x0 += ks1; x1 += ks2 + 4u;
    x0 += x1; x1 = rotl32(x1, 13); x1 ^= x0;
    x0 += x1; x1 = rotl32(x1, 15); x1 ^= x0;
    x0 += x1; x1 = rotl32(x1, 26); x1 ^= x0;
    x0 += x1; x1 = rotl32(x1,  6); x1 ^= x0;
    x0 += ks2; x1 += ks0 + 5u;
    *o0 = x0; *o1 = x1;
}

// ---- kernel A: per-chunk histogram (mask read exactly once, full GPU) ----
__global__ void icl_hist_kernel(const int* __restrict__ mask, int* __restrict__ ws) {
    const int c = blockIdx.x;           // chunk
    const int tid = threadIdx.x;        // 256 threads, 4 elements each
    __shared__ int h[64];
    if (tid < 64) h[tid] = 0;
    if (c == 0 && tid == 0) ws[WS_CTR] = 0;   // reset done-counter each call
    __syncthreads();
    const int4 v = ((const int4*)(mask + c * CHUNK))[tid];
    if ((unsigned)v.x < 64u) atomicAdd(&h[v.x], 1);
    if ((unsigned)v.y < 64u) atomicAdd(&h[v.y], 1);
    if ((unsigned)v.z < 64u) atomicAdd(&h[v.z], 1);
    if ((unsigned)v.w < 64u) atomicAdd(&h[v.w], 1);
    __syncthreads();
    if (tid < 64) ws[WS_HIST + tid * NCHUNK + c] = h[tid];   // transposed
}

// ---- kernel B: per-inst fused setup + resolve + dist + last-block final ----
__global__ void icl_inst_kernel(const int* __restrict__ mask,
                                const float* __restrict__ feats,
                                int* __restrict__ ws,
                                float* __restrict__ wsf,
                                float* __restrict__ out) {
    const int inst = blockIdx.x + 1;
    const int tid = threadIdx.x;        // 256 threads; tid == chunk index
    const int lane = tid & 63, wid = tid >> 6;   // 4 waves

    __shared__ int s_wsum[4];
    __shared__ int s_cnt;
    __shared__ unsigned s_bits[2];      // [0]=hi raw bits, [1]=lo raw bits
    __shared__ unsigned s_r;
    __shared__ int s_ch[3], s_k[3], s_idx[3];
    __shared__ float sred[8];
    __shared__ int s_last;

    if (tid < 3) { s_ch[tid] = -1; s_idx[tid] = 0; }

    // issue hist load first so threefry ALU overlaps its latency
    const int hh = ws[WS_HIST + inst * NCHUNK + tid];

    // raw random bits depend only on inst: tid0 -> hi chain, tid1 -> lo chain
    if (tid < 2) {
        unsigned f0, f1, ka, kb, b0, b1;
        threefry2x32(0u, 42u, 0u, (unsigned)inst, &f0, &f1);       // fold_in
        threefry2x32(f0, f1, 0u, (unsigned)tid, &ka, &kb);         // split: k1/k2
        threefry2x32(ka, kb, 0u, 0u, &b0, &b1);                    // random_bits
        s_bits[tid] = b0 ^ b1;
    }

    // ---- block scan of per-chunk hist counts ----
    int x = hh;
    for (int off = 1; off < 64; off <<= 1) {
        int y = __shfl_up(x, off, 64);
        if (lane >= off) x += y;
    }
    if (lane == 63) s_wsum[wid] = x;
    __syncthreads();                                   // B1
    int add = 0;
    for (int w = 0; w < wid; w++) add += s_wsum[w];
    const int incl = x + add;
    const int excl = incl - hh;
    if (tid == 255) s_cnt = incl;
    // match-task owners (need only local incl/excl)
    if (excl == 0 && incl >= 1) { s_ch[0] = tid; s_k[0] = 1; }
    if (excl <  2 && incl >= 2) { s_ch[1] = tid; s_k[1] = 2 - excl; }
    __syncthreads();                                   // B2: s_cnt, s_bits visible

    const int cnt  = s_cnt;
    const int ncnt = HW_N - cnt;
    if (tid == 0) {
        const unsigned span = (unsigned)((ncnt > 1) ? ncnt : 1);
        const unsigned hi = s_bits[0], lo = s_bits[1];
        unsigned mult = 65536u % span;
        mult = (mult * mult) % span;                   // u32 wrap, like lax.mul
        s_r = ((hi % span) * mult + (lo % span)) % span;
    }
    __syncthreads();                                   // B3: s_r visible

    // negative-task owner: (r+1)-th nonmatch
    const long long target = (long long)s_r + 1;
    const long long negincl = (long long)(tid + 1) * CHUNK - incl;
    const long long negexcl = (long long)tid * CHUNK - excl;
    if (negexcl < target && target <= negincl) {
        s_ch[2] = tid; s_k[2] = (int)(target - negexcl);
    }
    __syncthreads();                                   // B4: s_ch/s_k visible

    // ---- concurrent resolves: wave t handles task t (no barriers inside) ----
    if (wid < 3) {
        const int t = wid;
        const int chunk = s_ch[t];                     // wave-uniform
        if (chunk >= 0) {
            const int k = s_k[t];
            // this wave reads the whole 1024-elem chunk: 16 elems per lane
            const int4* cp = (const int4*)(mask + chunk * CHUNK) + lane * 4;
            unsigned fm = 0;
            #pragma unroll
            for (int j = 0; j < 4; j++) {
                const int4 v = cp[j];
                fm |= (unsigned)(v.x == inst) << (4 * j + 0);
                fm |= (unsigned)(v.y == inst) << (4 * j + 1);
                fm |= (unsigned)(v.z == inst) << (4 * j + 2);
                fm |= (unsigned)(v.w == inst) << (4 * j + 3);
            }
            if (t == 2) fm ^= 0xFFFFu;                 // negatives
            const int pc = __popc(fm);
            int sx = pc;
            for (int off = 1; off < 64; off <<= 1) {
                int y = __shfl_up(sx, off, 64);
                if (lane >= off) sx += y;
            }
            const int pre = sx - pc;
            if (pre < k && k <= sx) {
                int need = k - pre;
                int j = 0;
                while (true) {
                    if (fm & (1u << j)) { if (--need == 0) break; }
                    j++;
                }
                s_idx[t] = chunk * CHUNK + lane * 16 + j;
            }
        }
    }
    __syncthreads();                                   // B5: s_idx visible

    // ---- dist: gather 3 columns, hinge ----
    const int valid = (cnt >= 2 && ncnt > 0) ? 1 : 0;
    const int iF = s_idx[0], iS = s_idx[1], iN = s_idx[2];
    float sap = 0.f, san = 0.f;
    if (valid) {
        for (int row = tid; row < ROWS; row += 256) {
            const size_t off = (size_t)row * HW_N;
            const float a = feats[off + iF];
            const float p = feats[off + iS];
            const float n = feats[off + iN];
            const float dp = a - p + 1e-6f;
            const float dn = a - n + 1e-6f;
            sap += dp * dp;
            san += dn * dn;
        }
    }
    for (int off = 32; off > 0; off >>= 1) {
        sap += __shfl_down(sap, off, 64);
        san += __shfl_down(san, off, 64);
    }
    if (lane == 0) { sred[wid] = sap; sred[4 + wid] = san; }
    __syncthreads();
    if (tid == 0) {
        float t1 = sred[0] + sred[1] + sred[2] + sred[3];
        float t2 = sred[4] + sred[5] + sred[6] + sred[7];
        const float l = fmaxf(sqrtf(t1) - sqrtf(t2) + 1.0f, 0.0f);
        wsf[inst] = valid ? l : 0.0f;
        ws[320 + inst] = valid;
        __threadfence();                                     // release
        const unsigned old = atomicAdd((unsigned*)&ws[WS_CTR], 1u);
        s_last = (old == NINST - 1);
    }
    __syncthreads();

    // ---- elected last block: deterministic final mean (fixed-order tree) ----
    if (s_last && tid < 64) {
        __threadfence();                                     // acquire
        float l = 0.f, v = 0.f;
        if (tid >= 1 && tid <= NINST) {
            l = __hip_atomic_load(&wsf[tid], __ATOMIC_RELAXED, __HIP_MEMORY_SCOPE_AGENT);
            v = (float)__hip_atomic_load(&ws[320 + tid], __ATOMIC_RELAXED, __HIP_MEMORY_SCOPE_AGENT);
        }
        for (int off = 32; off > 0; off >>= 1) {
            l += __shfl_down(l, off, 64);
            v += __shfl_down(v, off, 64);
        }
        if (tid == 0) out[0] = (v > 0.f) ? (l / fmaxf(v, 1.0f)) : 0.0f;
    }
}

extern "C" void kernel_launch(void* const* d_in, const int* in_sizes, int n_in,
                              void* d_out, int out_size, void* d_ws, size_t ws_size,
                              hipStream_t stream) {
    const float* feats = (const float*)d_in[0];   // (2,256,512,512) f32 -> (512, 262144)
    const int*   mask  = (const int*)d_in[1];     // (512,512) int32
    float* out = (float*)d_out;
    int*   wsi = (int*)d_ws;
    float* wsf = ((float*)d_ws) + 384;

    icl_hist_kernel <<<NCHUNK, 256, 0, stream>>>(mask, wsi);
    icl_inst_kernel <<<NINST, 256, 0, stream>>>(mask, feats, wsi, wsf, out);
}